// Round 11
// baseline (112.411 us; speedup 1.0000x reference)
//
#include <hip/hip_runtime.h>
#include <math.h>

#define L_SEQ 384
#define E_DIM 512
#define NHEAD 8
#define NBH   16
#define HD    64
#define LOG2E 1.44269504f

typedef __attribute__((ext_vector_type(8))) __bf16 bf16x8;
typedef __attribute__((ext_vector_type(8))) _Float16 f16x8;
typedef __attribute__((ext_vector_type(4))) float f32x4;

union u4h8 { uint4 u; f16x8 h; };

__device__ __forceinline__ float uniform_f(float v) {
  return __uint_as_float(__builtin_amdgcn_readfirstlane(__float_as_uint(v)));
}

__device__ __forceinline__ unsigned f2bf(float f) {   // RNE float->bf16 bits
  unsigned u = __float_as_uint(f);
  return (u + 0x7FFFu + ((u >> 16) & 1u)) >> 16;
}

__device__ __forceinline__ unsigned ror16(unsigned x) { return (x >> 16) | (x << 16); }

// quad_perm DPP helpers (aligned 4-lane groups)
__device__ __forceinline__ float dpp_xor1(float x) {
  return __int_as_float(__builtin_amdgcn_mov_dpp(__float_as_int(x), 0xB1, 0xF, 0xF, 0));
}
__device__ __forceinline__ float dpp_xor2(float x) {
  return __int_as_float(__builtin_amdgcn_mov_dpp(__float_as_int(x), 0x4E, 0xF, 0xF, 0));
}
template <int PAT>
__device__ __forceinline__ float quad_bcast(float x) {
  return __int_as_float(__builtin_amdgcn_mov_dpp(__float_as_int(x), PAT, 0xF, 0xF, 0));
}
template <int IMM>
__device__ __forceinline__ float swz_xor(float x) {   // ds_swizzle: imm must be literal
  return __int_as_float(__builtin_amdgcn_ds_swizzle(__float_as_int(x), IMM));
}

// Fragment-packed layout: a wave consumes one (16-row x 32-k) tile as
// lane(quad,mr) -> row=mr, k=quad*8..+7. Pack memory in exactly that order:
// [row/16][k/32][quad=(k>>3)&3][mr=row&15][e=k&7] -> coalesced 16B/lane loads.
__device__ __forceinline__ size_t pidx(int row, int k, int Kd) {
  return ((((size_t)(row >> 4) * (Kd >> 5) + (k >> 5)) * 4 + ((k >> 3) & 3)) * 16
          + (row & 15)) * 8 + (k & 7);
}

// Build the score A-frag R_c(qhat) from a raw packed qa register (2 atoms).
// Rebuilt per chunk from 8 live VGPRs instead of caching 32 (occupancy).
// R0=(w,-x,-y,-z)  R1=(x,w,-z,y)  R2=(y,z,w,-x)  R3=(z,-y,x,w)
template <int C>
__device__ __forceinline__ u4h8 build_fr(uint4 qa) {
  u4h8 f;
  if (C == 0) {
    f.u = make_uint4(qa.x ^ 0x80000000u, qa.y ^ 0x80008000u,
                     qa.z ^ 0x80000000u, qa.w ^ 0x80008000u);
  } else if (C == 1) {
    f.u = make_uint4(ror16(qa.x), ror16(qa.y) ^ 0x00008000u,
                     ror16(qa.z), ror16(qa.w) ^ 0x00008000u);
  } else if (C == 2) {
    f.u = make_uint4(qa.y, qa.x ^ 0x80000000u, qa.w, qa.z ^ 0x80000000u);
  } else {
    f.u = make_uint4(ror16(qa.y) ^ 0x80000000u, ror16(qa.x),
                     ror16(qa.w) ^ 0x80000000u, ror16(qa.z));
  }
  return f;
}

// ---------------------------------------------------------------------------
// Convert x|Wq|Wk|Wv (dst1) and Wo (dst2) to bf16 packed; also zero `out`
// (needed by the atomic out-projection; this kernel runs first).
// ---------------------------------------------------------------------------
__global__ __launch_bounds__(256) void to_bf16_all(
    const float* __restrict__ x, const float* __restrict__ Wq,
    const float* __restrict__ Wk, const float* __restrict__ Wv,
    const float* __restrict__ Wo, unsigned short* __restrict__ dst1,
    unsigned short* __restrict__ dst2, float* __restrict__ outz)
{
  int e0 = (blockIdx.x * 256 + threadIdx.x) * 4;
  if (e0 >= 1835008) return;
  if (e0 >= 1441792) {                       // zero the output buffer
    *(float4*)(outz + (e0 - 1441792)) = make_float4(0.f, 0.f, 0.f, 0.f);
    return;
  }
  const float* src; unsigned short* d; int s;
  if (e0 < 393216)       { src = x;  s = e0;           d = dst1; }
  else if (e0 < 655360)  { src = Wq; s = e0 - 393216;  d = dst1 + 393216; }
  else if (e0 < 917504)  { src = Wk; s = e0 - 655360;  d = dst1 + 655360; }
  else if (e0 < 1179648) { src = Wv; s = e0 - 917504;  d = dst1 + 917504; }
  else                   { src = Wo; s = e0 - 1179648; d = dst2; }
  float4 v = *(const float4*)(src + s);
  unsigned lo = f2bf(v.x) | (f2bf(v.y) << 16);
  unsigned hi = f2bf(v.z) | (f2bf(v.w) << 16);
  int row = s >> 9, k = s & 511;
  *(uint2*)(d + pidx(row, k, 512)) = make_uint2(lo, hi);
}

// ---------------------------------------------------------------------------
// QKV GEMM v2: z=0 -> Q (16 MFMA, normalize, qhat); z=1 -> K AND V in one
// block (32 MFMA, A-loads shared): epilogue normalizes K (DPP quad-sum),
// stores khat, and builds Z0 DIRECTLY from in-register khat (f32) and
// V via 4 quad-broadcast DPPs. grid (32, 12, 2) = 768 blocks.
// ---------------------------------------------------------------------------
__global__ __launch_bounds__(256) void gemm_qkv(
    const __bf16* __restrict__ A, const __bf16* __restrict__ B0,
    const __bf16* __restrict__ B1, const __bf16* __restrict__ B2,
    _Float16* __restrict__ qhh, _Float16* __restrict__ khh,
    _Float16* __restrict__ Z0)
{
  const int z = blockIdx.z;
  const int tid = threadIdx.x;
  const int wave = tid >> 6, lane = tid & 63;
  const int m0 = blockIdx.y * 64 + wave * 16;
  const int n0 = blockIdx.x * 16;
  const int mr = lane & 15, quad = lane >> 4;
  const int KT = 16;                         // 512/32

  const __bf16* ap = A + (size_t)(m0 >> 4) * KT * 512 + lane * 8;
  const int n = n0 + mr;

  if (z == 0) {                              // ---- Q projection ----
    const __bf16* bp = B0 + (size_t)(n0 >> 4) * KT * 512 + lane * 8;
    f32x4 acc = (f32x4){0.f, 0.f, 0.f, 0.f};
    #pragma unroll 4
    for (int ks = 0; ks < KT; ++ks) {
      bf16x8 a = *(const bf16x8*)(ap + (size_t)ks * 512);
      bf16x8 b = *(const bf16x8*)(bp + (size_t)ks * 512);
      acc = __builtin_amdgcn_mfma_f32_16x16x32_bf16(a, b, acc, 0, 0, 0);
    }
    #pragma unroll
    for (int r = 0; r < 4; ++r) {
      float val = acc[r];
      float s = val * val;
      s += dpp_xor1(s);
      s += dpp_xor2(s);                      // |atom|^2 across component lanes
      float sc = __builtin_amdgcn_rsqf(fmaxf(s, 1e-30f));
      int m = m0 + quad * 4 + r;
      int b = m / L_SEQ, l = m - b * L_SEQ;
      int row = (b * NHEAD + (n >> 6)) * L_SEQ + l;
      qhh[pidx(row, n & 63, 64)] = (_Float16)(val * sc);
    }
  } else {                                   // ---- K + V fused ----
    const __bf16* bpk = B1 + (size_t)(n0 >> 4) * KT * 512 + lane * 8;
    const __bf16* bpv = B2 + (size_t)(n0 >> 4) * KT * 512 + lane * 8;
    f32x4 accK = (f32x4){0.f, 0.f, 0.f, 0.f};
    f32x4 accV = (f32x4){0.f, 0.f, 0.f, 0.f};
    #pragma unroll 4
    for (int ks = 0; ks < KT; ++ks) {
      bf16x8 a = *(const bf16x8*)(ap + (size_t)ks * 512);
      bf16x8 bk = *(const bf16x8*)(bpk + (size_t)ks * 512);
      bf16x8 bv = *(const bf16x8*)(bpv + (size_t)ks * 512);
      accK = __builtin_amdgcn_mfma_f32_16x16x32_bf16(a, bk, accK, 0, 0, 0);
      accV = __builtin_amdgcn_mfma_f32_16x16x32_bf16(a, bv, accV, 0, 0, 0);
    }
    const int a_atom = (n & 63) >> 2, comp = n & 3;
    #pragma unroll
    for (int r = 0; r < 4; ++r) {
      float vk = accK[r], vv = accV[r];
      float s = vk * vk;
      s += dpp_xor1(s);
      s += dpp_xor2(s);
      float kn = vk * __builtin_amdgcn_rsqf(fmaxf(s, 1e-30f));
      int m = m0 + quad * 4 + r;
      int b = m / L_SEQ, l = m - b * L_SEQ;
      int bh = b * NHEAD + (n >> 6);
      int row = bh * L_SEQ + l;
      khh[pidx(row, n & 63, 64)] = (_Float16)kn;
      // v_e across the 4 component lanes (quad-aligned)
      float v0 = quad_bcast<0x00>(vv), v1 = quad_bcast<0x55>(vv);
      float v2 = quad_bcast<0xAA>(vv), v3 = quad_bcast<0xFF>(vv);
      _Float16* zp = Z0 + (size_t)bh * (256 * 384);
      int colb = a_atom * 16 + comp * 4;
      zp[pidx(colb + 0, l, 384)] = (_Float16)(kn * v0);
      zp[pidx(colb + 1, l, 384)] = (_Float16)(kn * v1);
      zp[pidx(colb + 2, l, 384)] = (_Float16)(kn * v2);
      zp[pidx(colb + 3, l, 384)] = (_Float16)(kn * v3);
    }
  }
}

// ---------------------------------------------------------------------------
// gate_pv v6 = R10 structure + J-SPLIT x2 WITHOUT slabs (R8's mistake):
// grid (24, 16, 2) = 768 blocks = exactly 3 blocks/CU (was 384 = 1.5/CU,
// a 2x load-imbalance tail), 3 chunks/block (half the barrier chain).
// Each half runs the full epilogue on its PARTIAL ctx (bf16 round + fused
// out-projection + f32 atomic-add) -- no slab traffic, no extra kernel.
// __launch_bounds__(256,3) + per-chunk rebuild of score A-frags from raw
// qa (8 VGPR, was 32) keep VGPR <= 170 so 3 blocks/CU is real.
// ---------------------------------------------------------------------------
__global__ __launch_bounds__(256, 3) void gate_pv(
    const _Float16* __restrict__ qhh, const _Float16* __restrict__ khh,
    const _Float16* __restrict__ Z0, const float* __restrict__ dde_w,
    const float* __restrict__ dde_b, const __bf16* __restrict__ Wob,
    float* __restrict__ out)
{
  __shared__ _Float16 gbuf[2][4096];    // [buf][c][ks2][quadk][row][e]
  __shared__ float qs[16][65];          // qhat f32, all 64 comps, +1 pad
  __shared__ __bf16 ctx_lds[16][72];    // ctx tile, +8 pad: conflict-free b128

  const int tid = threadIdx.x, w = tid >> 6, lane = tid & 63;
  const int mr = lane & 15, quad = lane >> 4;
  const int bh = blockIdx.y, ib = blockIdx.x, jh = blockIdx.z;
  const int i0 = ib * 16;

  {  // stage qhat f32: 16 rows x 64 comps (4 comps/thread)
    int il = tid >> 4, k4 = (tid & 15) * 4;
    union { uint2 u; _Float16 h[4]; } cv;
    cv.u = *(const uint2*)(qhh + pidx(bh * L_SEQ + i0 + il, k4, 64));
    qs[il][k4 + 0] = (float)cv.h[0]; qs[il][k4 + 1] = (float)cv.h[1];
    qs[il][k4 + 2] = (float)cv.h[2]; qs[il][k4 + 3] = (float)cv.h[3];
  }

  float wn[16], bn[4];                   // uniform -> SGPR
  #pragma unroll
  for (int t = 0; t < 16; ++t) wn[t] = uniform_f(dde_w[t]) * (-LOG2E * 0.0625f);
  #pragma unroll
  for (int c = 0; c < 4; ++c) bn[c] = uniform_f(dde_b[c]) * (-LOG2E);

  // raw qhat A-frag words for the i-strip (8 VGPR; fr rebuilt per use)
  uint4 qa[2];
  {
    const _Float16* ap = qhh + ((size_t)(bh * 24 + ib)) * 2 * 512 + lane * 8;
    qa[0] = *(const uint4*)(ap);
    qa[1] = *(const uint4*)(ap + 512);
  }

  const int bq = mr >> 2, e = mr & 3;
  // sgn_c(b) nibbles {E,4,8,2} -> 0x284E; tau(c,e) nibbles {0,A,6,C} -> 0xC6A0
  unsigned msk[4];
  #pragma unroll
  for (int c = 0; c < 4; ++c)
    msk[c] = ((((0x284Eu >> (c * 4 + bq)) ^ (0xC6A0u >> (c * 4 + e))) & 1u) << 31);

  f32x4 acc[4][4];                       // [c][nt] PV accumulators (cg = w)
  #pragma unroll
  for (int c = 0; c < 4; ++c)
    #pragma unroll
    for (int nt = 0; nt < 4; ++nt) acc[c][nt] = (f32x4){0.f, 0.f, 0.f, 0.f};

  const int jl = w * 16 + mr;            // this lane's j within the chunk
  const int gw = (jl >> 3) * 128 + (jl & 7) + quad * 32;  // gbuf write base

  // kb ping-pong prefetch: prologue loads this half's first chunk
  u4h8 kbp[2][2];                        // [buf][ks]
  {
    const _Float16* bp = khh + ((size_t)(bh * 24 + jh * 12 + w)) * 2 * 512 + lane * 8;
    kbp[0][0].h = *(const f16x8*)(bp);
    kbp[0][1].h = *(const f16x8*)(bp + 512);
  }

  #pragma unroll
  for (int ci = 0; ci < 3; ++ci) {
    const int ch = jh * 3 + ci;
    const int cur = ci & 1, nxt = cur ^ 1;
    // PV Z0 frags (consumed only after the barrier: latency self-hiding)
    u4h8 zb[2][4];
    #pragma unroll
    for (int ks2 = 0; ks2 < 2; ++ks2)
      #pragma unroll
      for (int nt = 0; nt < 4; ++nt)
        zb[ks2][nt].h = *(const f16x8*)(Z0 + (size_t)bh * (256 * 384)
                         + (((size_t)(w * 4 + nt) * 12 + ch * 2 + ks2) * 512) + lane * 8);

    // SCORE with the PREFETCHED kb; A-frags rebuilt from qa (compile-time c)
    f32x4 accS[4];
    {
      u4h8 f00 = build_fr<0>(qa[0]), f01 = build_fr<0>(qa[1]);
      accS[0] = (f32x4){0.f, 0.f, 0.f, 0.f};
      accS[0] = __builtin_amdgcn_mfma_f32_16x16x32_f16(f00.h, kbp[cur][0].h, accS[0], 0, 0, 0);
      accS[0] = __builtin_amdgcn_mfma_f32_16x16x32_f16(f01.h, kbp[cur][1].h, accS[0], 0, 0, 0);
      u4h8 f10 = build_fr<1>(qa[0]), f11 = build_fr<1>(qa[1]);
      accS[1] = (f32x4){0.f, 0.f, 0.f, 0.f};
      accS[1] = __builtin_amdgcn_mfma_f32_16x16x32_f16(f10.h, kbp[cur][0].h, accS[1], 0, 0, 0);
      accS[1] = __builtin_amdgcn_mfma_f32_16x16x32_f16(f11.h, kbp[cur][1].h, accS[1], 0, 0, 0);
      u4h8 f20 = build_fr<2>(qa[0]), f21 = build_fr<2>(qa[1]);
      accS[2] = (f32x4){0.f, 0.f, 0.f, 0.f};
      accS[2] = __builtin_amdgcn_mfma_f32_16x16x32_f16(f20.h, kbp[cur][0].h, accS[2], 0, 0, 0);
      accS[2] = __builtin_amdgcn_mfma_f32_16x16x32_f16(f21.h, kbp[cur][1].h, accS[2], 0, 0, 0);
      u4h8 f30 = build_fr<3>(qa[0]), f31 = build_fr<3>(qa[1]);
      accS[3] = (f32x4){0.f, 0.f, 0.f, 0.f};
      accS[3] = __builtin_amdgcn_mfma_f32_16x16x32_f16(f30.h, kbp[cur][0].h, accS[3], 0, 0, 0);
      accS[3] = __builtin_amdgcn_mfma_f32_16x16x32_f16(f31.h, kbp[cur][1].h, accS[3], 0, 0, 0);
    }

    // prefetch kb for the next chunk (hides under gate+barrier+PV)
    if (ci < 2) {
      const _Float16* bp = khh
          + ((size_t)(bh * 24 + (ch + 1) * 4 + w)) * 2 * 512 + lane * 8;
      kbp[nxt][0].h = *(const f16x8*)(bp);
      kbp[nxt][1].h = *(const f16x8*)(bp + 512);
    }

    // GATE: 16 sigmoids -> f16 A-frag positions in LDS (buffer cur)
    #pragma unroll
    for (int r = 0; r < 4; ++r) {
      float S0 = accS[0][r], S1 = accS[1][r], S2 = accS[2][r], S3 = accS[3][r];
      #pragma unroll
      for (int c = 0; c < 4; ++c) {
        float n = bn[c] + wn[c*4+0]*S0 + wn[c*4+1]*S1 + wn[c*4+2]*S2 + wn[c*4+3]*S3;
        float g = __builtin_amdgcn_rcpf(1.f + __builtin_amdgcn_exp2f(n));
        gbuf[cur][c * 1024 + gw + r * 8] = (_Float16)g;
      }
    }
    __syncthreads();                     // single barrier/chunk (dbuf'd gbuf)

    // PV: wave w = cg; all 4 c against its Z0 slice
    #pragma unroll
    for (int ks2 = 0; ks2 < 2; ++ks2) {
      #pragma unroll
      for (int c = 0; c < 4; ++c) {
        f16x8 aa = *(const f16x8*)&gbuf[cur][c * 1024 + ks2 * 512 + lane * 8];
        #pragma unroll
        for (int nt = 0; nt < 4; ++nt)
          acc[c][nt] = __builtin_amdgcn_mfma_f32_16x16x32_f16(aa, zb[ks2][nt].h, acc[c][nt], 0, 0, 0);
      }
    }
  }

  // EPILOGUE 1 (intra-wave Klein butterfly): signed-q multiply, b-reduce
  // (^4,^8), permuted e-stages; lane mr==0 stores bf16 partial ctx into LDS.
  #pragma unroll
  for (int nt = 0; nt < 4; ++nt) {
    #pragma unroll
    for (int r = 0; r < 4; ++r) {
      int il = quad * 4 + r;
      float pb[4];
      #pragma unroll
      for (int c = 0; c < 4; ++c) {
        float sq = __uint_as_float(
            __float_as_uint(qs[il][w * 16 + nt * 4 + (bq ^ c)]) ^ msk[c]);
        float v = sq * acc[c][nt][r];
        v += swz_xor<0x101F>(v);
        v += swz_xor<0x201F>(v);
        pb[c] = v;
      }
      float q0 = pb[0] + dpp_xor1(pb[1]);
      float q1 = pb[1] + dpp_xor1(pb[0]);
      float q2 = pb[2] + dpp_xor1(pb[3]);
      float q3 = pb[3] + dpp_xor1(pb[2]);
      float r0 = q0 + dpp_xor2(q2);
      float r1 = q1 + dpp_xor2(q3);
      float r2 = q2 + dpp_xor2(q0);
      float r3 = q3 + dpp_xor2(q1);
      if (mr == 0) {
        ctx_lds[il][w * 16 + nt * 4 + 0] = (__bf16)r0;
        ctx_lds[il][w * 16 + nt * 4 + 1] = (__bf16)r1;
        ctx_lds[il][w * 16 + nt * 4 + 2] = (__bf16)r2;
        ctx_lds[il][w * 16 + nt * 4 + 3] = (__bf16)r3;
      }
    }
  }
  __syncthreads();

  // EPILOGUE 2 (fused out-projection, K=64 h-split, per j-half): each wave
  // covers n = w*128 .. +128 (8 n-tiles); A-frag from ctx_lds, B-frag from
  // packed Wob k-slice [hh*64, hh*64+64); f32 atomic-add.
  const int bb_ = bh >> 3, hh = bh & 7;
  const int m_base = bb_ * L_SEQ + i0;
  bf16x8 af[2];
  #pragma unroll
  for (int ks2 = 0; ks2 < 2; ++ks2)
    af[ks2] = *(const bf16x8*)&ctx_lds[mr][ks2 * 32 + quad * 8];
  #pragma unroll
  for (int nt2 = 0; nt2 < 8; ++nt2) {
    const int ntile = w * 8 + nt2;       // n-tile index over 512
    f32x4 accO = (f32x4){0.f, 0.f, 0.f, 0.f};
    #pragma unroll
    for (int ks2 = 0; ks2 < 2; ++ks2) {
      bf16x8 b = *(const bf16x8*)(Wob + ((size_t)ntile * 16 + hh * 2 + ks2) * 512 + lane * 8);
      accO = __builtin_amdgcn_mfma_f32_16x16x32_bf16(af[ks2], b, accO, 0, 0, 0);
    }
    const int n = ntile * 16 + mr;
    #pragma unroll
    for (int r = 0; r < 4; ++r) {
      int m = m_base + quad * 4 + r;
      __hip_atomic_fetch_add(&out[(size_t)m * E_DIM + n], accO[r],
                             __ATOMIC_RELAXED, __HIP_MEMORY_SCOPE_AGENT);
    }
  }
}

// ---------------------------------------------------------------------------
// Workspace (8,388,608 B used):
//   [0        ..   524288)  Wob bf16 packed                [whole run]
//   [524288   ..  1310720)  qhat f16 packed                [gemm -> gate_pv]
//   [1310720  ..  2097152)  khat f16 packed                [gemm -> gate_pv]
//   [2097152  ..  5242880)  Z0 f16 packed                  [gemm -> gate_pv]
//   [6029312  ..  8388608)  xb|Wqb|Wkb|Wvb bf16 packed     [cvt -> gemm]
// ---------------------------------------------------------------------------
extern "C" void kernel_launch(void* const* d_in, const int* in_sizes, int n_in,
                              void* d_out, int out_size, void* d_ws, size_t ws_size,
                              hipStream_t stream)
{
  const float* x     = (const float*)d_in[0];
  const float* Wq    = (const float*)d_in[1];
  const float* Wk    = (const float*)d_in[2];
  const float* Wv    = (const float*)d_in[3];
  const float* Wo    = (const float*)d_in[4];
  const float* dde_w = (const float*)d_in[5];
  const float* dde_b = (const float*)d_in[6];
  float* out = (float*)d_out;

  char* ws = (char*)d_ws;
  unsigned short* Wob  = (unsigned short*)(ws + 0);
  _Float16* qhh = (_Float16*)(ws + 524288);
  _Float16* khh = (_Float16*)(ws + 1310720);
  _Float16* Z0h = (_Float16*)(ws + 2097152);
  unsigned short* xb  = (unsigned short*)(ws + 6029312);
  unsigned short* Wqb = (unsigned short*)(ws + 6815744);
  unsigned short* Wkb = (unsigned short*)(ws + 7340032);
  unsigned short* Wvb = (unsigned short*)(ws + 7864320);

  // 1) fp32 -> bf16 conversions (packed) + zero `out`
  to_bf16_all<<<1792, 256, 0, stream>>>(x, Wq, Wk, Wv, Wo, xb, Wob, out);

  // 2) Q | K+V projections; K+V epilogue emits khat AND Z0
  gemm_qkv<<<dim3(32, 12, 2), 256, 0, stream>>>(
      (const __bf16*)xb, (const __bf16*)Wqb, (const __bf16*)Wkb, (const __bf16*)Wvb,
      qhh, khh, Z0h);

  // 3) FUSED score+gate+PV+out-projection, j-split x2 -> atomic f32 out
  gate_pv<<<dim3(24, 16, 2), 256, 0, stream>>>(
      qhh, khh, Z0h, dde_w, dde_b, (const __bf16*)Wob, out);
}

// Round 12
// 101.292 us; speedup vs baseline: 1.1098x; 1.1098x over previous
//
#include <hip/hip_runtime.h>
#include <math.h>

#define L_SEQ 384
#define E_DIM 512
#define NHEAD 8
#define NBH   16
#define HD    64
#define LOG2E 1.44269504f

typedef __attribute__((ext_vector_type(8))) __bf16 bf16x8;
typedef __attribute__((ext_vector_type(8))) _Float16 f16x8;
typedef __attribute__((ext_vector_type(4))) float f32x4;

union u4h8 { uint4 u; f16x8 h; };

__device__ __forceinline__ float uniform_f(float v) {
  return __uint_as_float(__builtin_amdgcn_readfirstlane(__float_as_uint(v)));
}

__device__ __forceinline__ unsigned f2bf(float f) {   // RNE float->bf16 bits
  unsigned u = __float_as_uint(f);
  return (u + 0x7FFFu + ((u >> 16) & 1u)) >> 16;
}

__device__ __forceinline__ unsigned ror16(unsigned x) { return (x >> 16) | (x << 16); }

// quad_perm DPP helpers (aligned 4-lane groups)
__device__ __forceinline__ float dpp_xor1(float x) {
  return __int_as_float(__builtin_amdgcn_mov_dpp(__float_as_int(x), 0xB1, 0xF, 0xF, 0));
}
__device__ __forceinline__ float dpp_xor2(float x) {
  return __int_as_float(__builtin_amdgcn_mov_dpp(__float_as_int(x), 0x4E, 0xF, 0xF, 0));
}
template <int PAT>
__device__ __forceinline__ float quad_bcast(float x) {
  return __int_as_float(__builtin_amdgcn_mov_dpp(__float_as_int(x), PAT, 0xF, 0xF, 0));
}
template <int IMM>
__device__ __forceinline__ float swz_xor(float x) {   // ds_swizzle: imm must be literal
  return __int_as_float(__builtin_amdgcn_ds_swizzle(__float_as_int(x), IMM));
}

// Fragment-packed layout: a wave consumes one (16-row x 32-k) tile as
// lane(quad,mr) -> row=mr, k=quad*8..+7. Pack memory in exactly that order:
// [row/16][k/32][quad=(k>>3)&3][mr=row&15][e=k&7] -> coalesced 16B/lane loads.
__device__ __forceinline__ size_t pidx(int row, int k, int Kd) {
  return ((((size_t)(row >> 4) * (Kd >> 5) + (k >> 5)) * 4 + ((k >> 3) & 3)) * 16
          + (row & 15)) * 8 + (k & 7);
}

// ---------------------------------------------------------------------------
// Convert x|Wq|Wk|Wv (dst1) and Wo (dst2) to bf16 packed; also zero `out`
// (needed by the atomic out-projection; this kernel runs first).
// ---------------------------------------------------------------------------
__global__ __launch_bounds__(256) void to_bf16_all(
    const float* __restrict__ x, const float* __restrict__ Wq,
    const float* __restrict__ Wk, const float* __restrict__ Wv,
    const float* __restrict__ Wo, unsigned short* __restrict__ dst1,
    unsigned short* __restrict__ dst2, float* __restrict__ outz)
{
  int e0 = (blockIdx.x * 256 + threadIdx.x) * 4;
  if (e0 >= 1835008) return;
  if (e0 >= 1441792) {                       // zero the output buffer
    *(float4*)(outz + (e0 - 1441792)) = make_float4(0.f, 0.f, 0.f, 0.f);
    return;
  }
  const float* src; unsigned short* d; int s;
  if (e0 < 393216)       { src = x;  s = e0;           d = dst1; }
  else if (e0 < 655360)  { src = Wq; s = e0 - 393216;  d = dst1 + 393216; }
  else if (e0 < 917504)  { src = Wk; s = e0 - 655360;  d = dst1 + 655360; }
  else if (e0 < 1179648) { src = Wv; s = e0 - 917504;  d = dst1 + 917504; }
  else                   { src = Wo; s = e0 - 1179648; d = dst2; }
  float4 v = *(const float4*)(src + s);
  unsigned lo = f2bf(v.x) | (f2bf(v.y) << 16);
  unsigned hi = f2bf(v.z) | (f2bf(v.w) << 16);
  int row = s >> 9, k = s & 511;
  *(uint2*)(d + pidx(row, k, 512)) = make_uint2(lo, hi);
}

// ---------------------------------------------------------------------------
// QKV GEMM v2: z=0 -> Q (16 MFMA, normalize, qhat); z=1 -> K AND V in one
// block (32 MFMA, A-loads shared): epilogue normalizes K (DPP quad-sum),
// stores khat, and builds Z0 DIRECTLY from in-register khat (f32) and
// V via 4 quad-broadcast DPPs. grid (32, 12, 2) = 768 blocks.
// ---------------------------------------------------------------------------
__global__ __launch_bounds__(256) void gemm_qkv(
    const __bf16* __restrict__ A, const __bf16* __restrict__ B0,
    const __bf16* __restrict__ B1, const __bf16* __restrict__ B2,
    _Float16* __restrict__ qhh, _Float16* __restrict__ khh,
    _Float16* __restrict__ Z0)
{
  const int z = blockIdx.z;
  const int tid = threadIdx.x;
  const int wave = tid >> 6, lane = tid & 63;
  const int m0 = blockIdx.y * 64 + wave * 16;
  const int n0 = blockIdx.x * 16;
  const int mr = lane & 15, quad = lane >> 4;
  const int KT = 16;                         // 512/32

  const __bf16* ap = A + (size_t)(m0 >> 4) * KT * 512 + lane * 8;
  const int n = n0 + mr;

  if (z == 0) {                              // ---- Q projection ----
    const __bf16* bp = B0 + (size_t)(n0 >> 4) * KT * 512 + lane * 8;
    f32x4 acc = (f32x4){0.f, 0.f, 0.f, 0.f};
    #pragma unroll 4
    for (int ks = 0; ks < KT; ++ks) {
      bf16x8 a = *(const bf16x8*)(ap + (size_t)ks * 512);
      bf16x8 b = *(const bf16x8*)(bp + (size_t)ks * 512);
      acc = __builtin_amdgcn_mfma_f32_16x16x32_bf16(a, b, acc, 0, 0, 0);
    }
    #pragma unroll
    for (int r = 0; r < 4; ++r) {
      float val = acc[r];
      float s = val * val;
      s += dpp_xor1(s);
      s += dpp_xor2(s);                      // |atom|^2 across component lanes
      float sc = __builtin_amdgcn_rsqf(fmaxf(s, 1e-30f));
      int m = m0 + quad * 4 + r;
      int b = m / L_SEQ, l = m - b * L_SEQ;
      int row = (b * NHEAD + (n >> 6)) * L_SEQ + l;
      qhh[pidx(row, n & 63, 64)] = (_Float16)(val * sc);
    }
  } else {                                   // ---- K + V fused ----
    const __bf16* bpk = B1 + (size_t)(n0 >> 4) * KT * 512 + lane * 8;
    const __bf16* bpv = B2 + (size_t)(n0 >> 4) * KT * 512 + lane * 8;
    f32x4 accK = (f32x4){0.f, 0.f, 0.f, 0.f};
    f32x4 accV = (f32x4){0.f, 0.f, 0.f, 0.f};
    #pragma unroll 4
    for (int ks = 0; ks < KT; ++ks) {
      bf16x8 a = *(const bf16x8*)(ap + (size_t)ks * 512);
      bf16x8 bk = *(const bf16x8*)(bpk + (size_t)ks * 512);
      bf16x8 bv = *(const bf16x8*)(bpv + (size_t)ks * 512);
      accK = __builtin_amdgcn_mfma_f32_16x16x32_bf16(a, bk, accK, 0, 0, 0);
      accV = __builtin_amdgcn_mfma_f32_16x16x32_bf16(a, bv, accV, 0, 0, 0);
    }
    const int a_atom = (n & 63) >> 2, comp = n & 3;
    #pragma unroll
    for (int r = 0; r < 4; ++r) {
      float vk = accK[r], vv = accV[r];
      float s = vk * vk;
      s += dpp_xor1(s);
      s += dpp_xor2(s);
      float kn = vk * __builtin_amdgcn_rsqf(fmaxf(s, 1e-30f));
      int m = m0 + quad * 4 + r;
      int b = m / L_SEQ, l = m - b * L_SEQ;
      int bh = b * NHEAD + (n >> 6);
      int row = bh * L_SEQ + l;
      khh[pidx(row, n & 63, 64)] = (_Float16)kn;
      // v_e across the 4 component lanes (quad-aligned)
      float v0 = quad_bcast<0x00>(vv), v1 = quad_bcast<0x55>(vv);
      float v2 = quad_bcast<0xAA>(vv), v3 = quad_bcast<0xFF>(vv);
      _Float16* zp = Z0 + (size_t)bh * (256 * 384);
      int colb = a_atom * 16 + comp * 4;
      zp[pidx(colb + 0, l, 384)] = (_Float16)(kn * v0);
      zp[pidx(colb + 1, l, 384)] = (_Float16)(kn * v1);
      zp[pidx(colb + 2, l, 384)] = (_Float16)(kn * v2);
      zp[pidx(colb + 3, l, 384)] = (_Float16)(kn * v3);
    }
  }
}

// ---------------------------------------------------------------------------
// gate_pv v5 (R10, best measured): score-once fusion, kb ping-pong prefetch,
// fused out-projection. Block = 4 waves owns (i-strip 16, bh);
// grid (24, 16) = 384 blocks.
// Per 64-j chunk (6):
//   SCORE: wave w scores its own 16-j subtile for ALL 4 c (8 MFMA) using
//          the PREFETCHED kb (no same-chunk load dependency).
//   GATE:  16 sigmoids/lane -> f16 LDS gbuf in MFMA A-frag order
//          (double-buffered -> ONE barrier per chunk).
//   PV:    wave w owns cg=w: for all 4 c, acc[c][nt] += mfma(G_c, Z0_cg).
// Epilogue: intra-wave Klein butterfly -> bf16 ctx tile in padded LDS ->
// fused out-projection (K=64 h-split) with f32 atomic-add.
// (R11's j-split x2 regressed +11us: duplicated epilogue/atomics and the
// (256,3) VGPR cap; do not re-attempt without spill evidence.)
// ---------------------------------------------------------------------------
__global__ __launch_bounds__(256) void gate_pv(
    const _Float16* __restrict__ qhh, const _Float16* __restrict__ khh,
    const _Float16* __restrict__ Z0, const float* __restrict__ dde_w,
    const float* __restrict__ dde_b, const __bf16* __restrict__ Wob,
    float* __restrict__ out)
{
  __shared__ _Float16 gbuf[2][4096];    // [buf][c][ks2][quadk][row][e]
  __shared__ float qs[16][65];          // qhat f32, all 64 comps, +1 pad
  __shared__ __bf16 ctx_lds[16][72];    // ctx tile, +8 pad: conflict-free b128

  const int tid = threadIdx.x, w = tid >> 6, lane = tid & 63;
  const int mr = lane & 15, quad = lane >> 4;
  const int bh = blockIdx.y, ib = blockIdx.x;
  const int i0 = ib * 16;

  {  // stage qhat f32: 16 rows x 64 comps (4 comps/thread)
    int il = tid >> 4, k4 = (tid & 15) * 4;
    union { uint2 u; _Float16 h[4]; } cv;
    cv.u = *(const uint2*)(qhh + pidx(bh * L_SEQ + i0 + il, k4, 64));
    qs[il][k4 + 0] = (float)cv.h[0]; qs[il][k4 + 1] = (float)cv.h[1];
    qs[il][k4 + 2] = (float)cv.h[2]; qs[il][k4 + 3] = (float)cv.h[3];
  }

  float wn[16], bn[4];
  #pragma unroll
  for (int t = 0; t < 16; ++t) wn[t] = uniform_f(dde_w[t]) * (-LOG2E * 0.0625f);
  #pragma unroll
  for (int c = 0; c < 4; ++c) bn[c] = uniform_f(dde_b[c]) * (-LOG2E);

  // score A-frags R_c(qhat) for the i-strip (built once; 32 VGPR)
  u4h8 fr[4][2];
  {
    const _Float16* ap = qhh + ((size_t)(bh * 24 + ib)) * 2 * 512 + lane * 8;
    #pragma unroll
    for (int ks = 0; ks < 2; ++ks) {
      uint4 qa = *(const uint4*)(ap + ks * 512);
      unsigned s0 = ror16(qa.x), s1 = ror16(qa.y), s2 = ror16(qa.z), s3 = ror16(qa.w);
      // R0=(w,-x,-y,-z)  R1=(x,w,-z,y)  R2=(y,z,w,-x)  R3=(z,-y,x,w)
      fr[0][ks].u = make_uint4(qa.x ^ 0x80000000u, qa.y ^ 0x80008000u,
                               qa.z ^ 0x80000000u, qa.w ^ 0x80008000u);
      fr[1][ks].u = make_uint4(s0, s1 ^ 0x00008000u, s2, s3 ^ 0x00008000u);
      fr[2][ks].u = make_uint4(qa.y, qa.x ^ 0x80000000u, qa.w, qa.z ^ 0x80000000u);
      fr[3][ks].u = make_uint4(s1 ^ 0x80000000u, s0, s3 ^ 0x80000000u, s2);
    }
  }

  const int bq = mr >> 2, e = mr & 3;
  // sgn_c(b) nibbles {E,4,8,2} -> 0x284E; tau(c,e) nibbles {0,A,6,C} -> 0xC6A0
  unsigned msk[4];
  #pragma unroll
  for (int c = 0; c < 4; ++c)
    msk[c] = ((((0x284Eu >> (c * 4 + bq)) ^ (0xC6A0u >> (c * 4 + e))) & 1u) << 31);

  f32x4 acc[4][4];                       // [c][nt] PV accumulators (cg = w)
  #pragma unroll
  for (int c = 0; c < 4; ++c)
    #pragma unroll
    for (int nt = 0; nt < 4; ++nt) acc[c][nt] = (f32x4){0.f, 0.f, 0.f, 0.f};

  const int jl = w * 16 + mr;            // this lane's j within the chunk
  const int gw = (jl >> 3) * 128 + (jl & 7) + quad * 32;  // gbuf write base

  // kb ping-pong prefetch: prologue loads chunk 0
  u4h8 kbp[2][2];                        // [buf][ks]
  {
    const _Float16* bp = khh + ((size_t)(bh * 24 + w)) * 2 * 512 + lane * 8;
    kbp[0][0].h = *(const f16x8*)(bp);
    kbp[0][1].h = *(const f16x8*)(bp + 512);
  }

  #pragma unroll
  for (int ch = 0; ch < 6; ++ch) {
    const int cur = ch & 1, nxt = cur ^ 1;
    // PV Z0 frags (consumed only after the barrier: latency self-hiding)
    u4h8 zb[2][4];
    #pragma unroll
    for (int ks2 = 0; ks2 < 2; ++ks2)
      #pragma unroll
      for (int nt = 0; nt < 4; ++nt)
        zb[ks2][nt].h = *(const f16x8*)(Z0 + (size_t)bh * (256 * 384)
                         + (((size_t)(w * 4 + nt) * 12 + ch * 2 + ks2) * 512) + lane * 8);

    // SCORE with the PREFETCHED kb (no same-chunk load dependency)
    f32x4 accS[4];
    #pragma unroll
    for (int c = 0; c < 4; ++c) {
      accS[c] = (f32x4){0.f, 0.f, 0.f, 0.f};
      accS[c] = __builtin_amdgcn_mfma_f32_16x16x32_f16(fr[c][0].h, kbp[cur][0].h, accS[c], 0, 0, 0);
      accS[c] = __builtin_amdgcn_mfma_f32_16x16x32_f16(fr[c][1].h, kbp[cur][1].h, accS[c], 0, 0, 0);
    }

    // prefetch kb for chunk ch+1 (hides under gate+barrier+PV)
    if (ch < 5) {
      const _Float16* bp = khh + ((size_t)(bh * 24 + (ch + 1) * 4 + w)) * 2 * 512 + lane * 8;
      kbp[nxt][0].h = *(const f16x8*)(bp);
      kbp[nxt][1].h = *(const f16x8*)(bp + 512);
    }

    // GATE: 16 sigmoids -> f16 A-frag positions in LDS (buffer cur)
    #pragma unroll
    for (int r = 0; r < 4; ++r) {
      float S0 = accS[0][r], S1 = accS[1][r], S2 = accS[2][r], S3 = accS[3][r];
      #pragma unroll
      for (int c = 0; c < 4; ++c) {
        float n = bn[c] + wn[c*4+0]*S0 + wn[c*4+1]*S1 + wn[c*4+2]*S2 + wn[c*4+3]*S3;
        float g = __builtin_amdgcn_rcpf(1.f + __builtin_amdgcn_exp2f(n));
        gbuf[cur][c * 1024 + gw + r * 8] = (_Float16)g;
      }
    }
    __syncthreads();                     // single barrier/chunk (dbuf'd gbuf)

    // PV: wave w = cg; all 4 c against its Z0 slice
    #pragma unroll
    for (int ks2 = 0; ks2 < 2; ++ks2) {
      #pragma unroll
      for (int c = 0; c < 4; ++c) {
        f16x8 aa = *(const f16x8*)&gbuf[cur][c * 1024 + ks2 * 512 + lane * 8];
        #pragma unroll
        for (int nt = 0; nt < 4; ++nt)
          acc[c][nt] = __builtin_amdgcn_mfma_f32_16x16x32_f16(aa, zb[ks2][nt].h, acc[c][nt], 0, 0, 0);
      }
    }
  }

  // EPILOGUE 1 (intra-wave Klein butterfly): signed-q multiply, b-reduce
  // (^4,^8), permuted e-stages; lane mr==0 stores bf16 ctx (ONE RNE round)
  // into the padded LDS tile.
  #pragma unroll
  for (int nt = 0; nt < 4; ++nt) {
    #pragma unroll
    for (int r = 0; r < 4; ++r) {
      int il = quad * 4 + r;
      float pb[4];
      #pragma unroll
      for (int c = 0; c < 4; ++c) {
        float sq = __uint_as_float(
            __float_as_uint(qs[il][w * 16 + nt * 4 + (bq ^ c)]) ^ msk[c]);
        float v = sq * acc[c][nt][r];
        v += swz_xor<0x101F>(v);
        v += swz_xor<0x201F>(v);
        pb[c] = v;
      }
      float q0 = pb[0] + dpp_xor1(pb[1]);
      float q1 = pb[1] + dpp_xor1(pb[0]);
      float q2 = pb[2] + dpp_xor1(pb[3]);
      float q3 = pb[3] + dpp_xor1(pb[2]);
      float r0 = q0 + dpp_xor2(q2);
      float r1 = q1 + dpp_xor2(q3);
      float r2 = q2 + dpp_xor2(q0);
      float r3 = q3 + dpp_xor2(q1);
      if (mr == 0) {
        ctx_lds[il][w * 16 + nt * 4 + 0] = (__bf16)r0;
        ctx_lds[il][w * 16 + nt * 4 + 1] = (__bf16)r1;
        ctx_lds[il][w * 16 + nt * 4 + 2] = (__bf16)r2;
        ctx_lds[il][w * 16 + nt * 4 + 3] = (__bf16)r3;
      }
    }
  }
  __syncthreads();

  // EPILOGUE 2 (fused out-projection, K=64 h-split): each wave covers
  // n = w*128 .. +128 (8 n-tiles); A-frag from ctx_lds, B-frag from packed
  // Wob k-slice [hh*64, hh*64+64); f32 atomic-add.
  const int bb_ = bh >> 3, hh = bh & 7;
  const int m_base = bb_ * L_SEQ + i0;
  bf16x8 af[2];
  #pragma unroll
  for (int ks2 = 0; ks2 < 2; ++ks2)
    af[ks2] = *(const bf16x8*)&ctx_lds[mr][ks2 * 32 + quad * 8];
  #pragma unroll
  for (int nt2 = 0; nt2 < 8; ++nt2) {
    const int ntile = w * 8 + nt2;       // n-tile index over 512
    f32x4 accO = (f32x4){0.f, 0.f, 0.f, 0.f};
    #pragma unroll
    for (int ks2 = 0; ks2 < 2; ++ks2) {
      bf16x8 b = *(const bf16x8*)(Wob + ((size_t)ntile * 16 + hh * 2 + ks2) * 512 + lane * 8);
      accO = __builtin_amdgcn_mfma_f32_16x16x32_bf16(af[ks2], b, accO, 0, 0, 0);
    }
    const int n = ntile * 16 + mr;
    #pragma unroll
    for (int r = 0; r < 4; ++r) {
      int m = m_base + quad * 4 + r;
      __hip_atomic_fetch_add(&out[(size_t)m * E_DIM + n], accO[r],
                             __ATOMIC_RELAXED, __HIP_MEMORY_SCOPE_AGENT);
    }
  }
}

// ---------------------------------------------------------------------------
// Workspace (8,388,608 B used):
//   [0        ..   524288)  Wob bf16 packed                [whole run]
//   [524288   ..  1310720)  qhat f16 packed                [gemm -> gate_pv]
//   [1310720  ..  2097152)  khat f16 packed                [gemm -> gate_pv]
//   [2097152  ..  5242880)  Z0 f16 packed                  [gemm -> gate_pv]
//   [6029312  ..  8388608)  xb|Wqb|Wkb|Wvb bf16 packed     [cvt -> gemm]
// ---------------------------------------------------------------------------
extern "C" void kernel_launch(void* const* d_in, const int* in_sizes, int n_in,
                              void* d_out, int out_size, void* d_ws, size_t ws_size,
                              hipStream_t stream)
{
  const float* x     = (const float*)d_in[0];
  const float* Wq    = (const float*)d_in[1];
  const float* Wk    = (const float*)d_in[2];
  const float* Wv    = (const float*)d_in[3];
  const float* Wo    = (const float*)d_in[4];
  const float* dde_w = (const float*)d_in[5];
  const float* dde_b = (const float*)d_in[6];
  float* out = (float*)d_out;

  char* ws = (char*)d_ws;
  unsigned short* Wob  = (unsigned short*)(ws + 0);
  _Float16* qhh = (_Float16*)(ws + 524288);
  _Float16* khh = (_Float16*)(ws + 1310720);
  _Float16* Z0h = (_Float16*)(ws + 2097152);
  unsigned short* xb  = (unsigned short*)(ws + 6029312);
  unsigned short* Wqb = (unsigned short*)(ws + 6815744);
  unsigned short* Wkb = (unsigned short*)(ws + 7340032);
  unsigned short* Wvb = (unsigned short*)(ws + 7864320);

  // 1) fp32 -> bf16 conversions (packed) + zero `out`
  to_bf16_all<<<1792, 256, 0, stream>>>(x, Wq, Wk, Wv, Wo, xb, Wob, out);

  // 2) Q | K+V projections; K+V epilogue emits khat AND Z0
  gemm_qkv<<<dim3(32, 12, 2), 256, 0, stream>>>(
      (const __bf16*)xb, (const __bf16*)Wqb, (const __bf16*)Wkb, (const __bf16*)Wvb,
      qhh, khh, Z0h);

  // 3) FUSED score+gate+PV+out-projection -> atomic f32 out
  gate_pv<<<dim3(24, 16), 256, 0, stream>>>(
      qhh, khh, Z0h, dde_w, dde_b, (const __bf16*)Wob, out);
}